// Round 1
// baseline (360.147 us; speedup 1.0000x reference)
//
#include <hip/hip_runtime.h>
#include <cstdint>

typedef _Float16 f16x8 __attribute__((ext_vector_type(8)));
typedef _Float16 f16x4 __attribute__((ext_vector_type(4)));
typedef float    f32x4 __attribute__((ext_vector_type(4)));

#define AS1 __attribute__((address_space(1)))
#define AS3 __attribute__((address_space(3)))

__device__ __forceinline__ void load16_lds(const void* g, void* l) {
  // 16B-per-lane async global->LDS. LDS dest is wave-uniform base + lane*16,
  // our tid-based mapping matches that exactly.
  __builtin_amdgcn_global_load_lds((AS1 void*)g, (AS3 void*)l, 16, 0, 0);
}

// ---------------- fp32 -> fp16 convert (vectorized) ----------------
__global__ __launch_bounds__(256) void cvt_f32_f16(const float* __restrict__ in,
                                                   _Float16* __restrict__ out, int n4) {
  int i = blockIdx.x * 256 + threadIdx.x;
  if (i >= n4) return;
  float4 v = ((const float4*)in)[i];
  f16x4 o;
  o[0] = (_Float16)v.x; o[1] = (_Float16)v.y; o[2] = (_Float16)v.z; o[3] = (_Float16)v.w;
  ((f16x4*)out)[i] = o;
}

// ---------------- causal softmax ----------------
// One block per row (g = b*2048 + i). Reads fp32 prefix [0..i], writes fp16 P
// into the UPPER HALF (byte offset +4096) of the same 8192-byte row, zero-padded
// up to the row's 128-tile edge so the PV GEMM never reads poison.
__global__ __launch_bounds__(256) void softmax_causal(float* __restrict__ Sbuf) {
  int g = blockIdx.x;
  int row = g & 2047;
  float* srow = Sbuf + (size_t)g * 2048;
  _Float16* prow = (_Float16*)srow + 2048;
  int L = row + 1;
  int Lp = ((row >> 7) + 1) << 7;
  int t = threadIdx.x;
  int lane = t & 63, w = t >> 6;

  float v[8];
  int cnt = 0;
  float mx = -3.0e38f;
  for (int j = t; j < L; j += 256) { float s = srow[j]; v[cnt++] = s; mx = fmaxf(mx, s); }

  __shared__ float sm[8];
  #pragma unroll
  for (int off = 32; off > 0; off >>= 1) mx = fmaxf(mx, __shfl_down(mx, off));
  if (lane == 0) sm[w] = mx;
  __syncthreads();
  if (t == 0) { float m2 = sm[0]; for (int q = 1; q < 4; q++) m2 = fmaxf(m2, sm[q]); sm[0] = m2; }
  __syncthreads();
  mx = sm[0];

  float sum = 0.f;
  for (int c = 0; c < cnt; c++) { float e = __expf(v[c] - mx); v[c] = e; sum += e; }
  #pragma unroll
  for (int off = 32; off > 0; off >>= 1) sum += __shfl_down(sum, off);
  if (lane == 0) sm[4 + w] = sum;
  __syncthreads();
  if (t == 0) sm[4] = 1.0f / (sm[4] + sm[5] + sm[6] + sm[7]);
  __syncthreads();
  float inv = sm[4];

  // all srow reads done (barriers above) -> safe to overwrite upper half
  cnt = 0;
  for (int j = t; j < L; j += 256) prow[j] = (_Float16)(v[cnt++] * inv);
  for (int j = L + t; j < Lp; j += 256) prow[j] = (_Float16)0.0f;
}

// ---------------- generic A * B^T GEMM, m97 structure ----------------
// A: [M x K] row-major fp16 (lda), B: [N x K] row-major fp16 (ldb), C = A*B^T.
// 128x128 tile per block, 256 threads = 4 waves (2x2), 4x4 MFMA 16x16x32 per wave.
// OUTMODE: 0 = fp16 normal, 1 = fp16 transposed (Vt[b][n][s], S=2048,D=1024 hardcoded),
//          2 = fp32 normal, 3 = fp32 + bias.
template <int OUTMODE, bool CAUSAL_SKIP, bool KCLAMP>
__global__ __launch_bounds__(256) void gemm_bt(
    const _Float16* __restrict__ A, const _Float16* __restrict__ B,
    void* __restrict__ Cv, const float* __restrict__ bias,
    int K, int lda, int ldb, int ldc,
    long long aBatch, long long bBatch, long long cBatch) {
  int bx = blockIdx.x, by = blockIdx.y, bz = blockIdx.z;
  if (CAUSAL_SKIP && bx > by) return;
  const _Float16* Ab = A + (long long)bz * aBatch + (long long)by * 128 * lda;
  const _Float16* Bb = B + (long long)bz * bBatch + (long long)bx * 128 * ldb;
  int kmax = K;
  if (KCLAMP) { int c = (by + 1) * 128; kmax = (c < K) ? c : K; }

  __shared__ _Float16 lA[128 * 32];
  __shared__ _Float16 lB[128 * 32];

  int tid = threadIdx.x;
  int r0 = tid >> 2;          // staging row 0..63 (+64 for second issue)
  int c0 = (tid & 3) * 8;     // staging col (8 halves = 16B)
  const _Float16* ga0 = Ab + (long long)r0 * lda + c0;
  const _Float16* ga1 = Ab + (long long)(r0 + 64) * lda + c0;
  const _Float16* gb0 = Bb + (long long)r0 * ldb + c0;
  const _Float16* gb1 = Bb + (long long)(r0 + 64) * ldb + c0;
  _Float16* la0 = lA + tid * 8;
  _Float16* la1 = lA + 2048 + tid * 8;
  _Float16* lb0 = lB + tid * 8;
  _Float16* lb1 = lB + 2048 + tid * 8;

  f32x4 acc[4][4] = {};
  int lane = tid & 63;
  int wv = tid >> 6;
  int wm = (wv & 1) * 64, wn = (wv >> 1) * 64;
  int l16 = lane & 15, quad = lane >> 4;
  const _Float16* raBase = lA + (wm + l16) * 32 + quad * 8;
  const _Float16* rbBase = lB + (wn + l16) * 32 + quad * 8;

  for (int kb = 0; kb < kmax; kb += 32) {
    __syncthreads();
    load16_lds(ga0, la0);
    load16_lds(ga1, la1);
    load16_lds(gb0, lb0);
    load16_lds(gb1, lb1);
    ga0 += 32; ga1 += 32; gb0 += 32; gb1 += 32;
    __syncthreads();
    f16x8 af[4], bfr[4];
    #pragma unroll
    for (int i = 0; i < 4; i++) af[i] = *(const f16x8*)(raBase + i * 512);
    #pragma unroll
    for (int j = 0; j < 4; j++) bfr[j] = *(const f16x8*)(rbBase + j * 512);
    #pragma unroll
    for (int i = 0; i < 4; i++)
      #pragma unroll
      for (int j = 0; j < 4; j++)
        acc[i][j] = __builtin_amdgcn_mfma_f32_16x16x32_f16(af[i], bfr[j], acc[i][j], 0, 0, 0);
  }

  // C/D layout (HW-verified): col = lane&15, row = quad*4 + reg
  int m0 = by * 128 + wm + quad * 4;
  int n0 = bx * 128 + wn + l16;

  if (OUTMODE == 0) {
    _Float16* C = (_Float16*)Cv + (long long)bz * cBatch;
    #pragma unroll
    for (int i = 0; i < 4; i++)
      #pragma unroll
      for (int j = 0; j < 4; j++)
        #pragma unroll
        for (int r = 0; r < 4; r++)
          C[(long long)(m0 + i * 16 + r) * ldc + (n0 + j * 16)] = (_Float16)acc[i][j][r];
  } else if (OUTMODE == 1) {
    // Vt[b][n][s]: b = m>>11, s = m&2047; 4 regs are 4 consecutive s -> 8B store
    _Float16* C = (_Float16*)Cv;
    #pragma unroll
    for (int i = 0; i < 4; i++) {
      long long mm = m0 + i * 16;
      long long b = mm >> 11;
      long long s = mm & 2047;
      #pragma unroll
      for (int j = 0; j < 4; j++) {
        f16x4 pk;
        #pragma unroll
        for (int r = 0; r < 4; r++) pk[r] = (_Float16)acc[i][j][r];
        *(f16x4*)(C + (b << 21) + (long long)(n0 + j * 16) * 2048 + s) = pk;
      }
    }
  } else if (OUTMODE == 2) {
    float* C = (float*)Cv + (long long)bz * cBatch;
    #pragma unroll
    for (int i = 0; i < 4; i++)
      #pragma unroll
      for (int j = 0; j < 4; j++)
        #pragma unroll
        for (int r = 0; r < 4; r++)
          C[(long long)(m0 + i * 16 + r) * ldc + (n0 + j * 16)] = acc[i][j][r];
  } else {
    float* C = (float*)Cv + (long long)bz * cBatch;
    #pragma unroll
    for (int j = 0; j < 4; j++) {
      float bj = bias[n0 + j * 16];
      #pragma unroll
      for (int i = 0; i < 4; i++)
        #pragma unroll
        for (int r = 0; r < 4; r++)
          C[(long long)(m0 + i * 16 + r) * ldc + (n0 + j * 16)] = acc[i][j][r] + bj;
    }
  }
}

// ---------------- workspace layout (bytes) ----------------
// xh : 0          16,777,216   x fp16 [8192][1024]
// Wq : 16777216    2,097,152
// Wk : 18874368    2,097,152
// Wv : 20971520    2,097,152
// Wo : 23068672    2,097,152
// Qh : 25165824   16,777,216   [b*2048+s][1024]
// Kh : 41943040   16,777,216
// Vt : 58720256   16,777,216   [b][d=1024][s=2048]
// Oh : 75497472   16,777,216   attn out fp16
// Sb : 92274688   67,108,864   fp32 scores [b*2048+q][2048]; fp16 P lives in
//                              upper 4KB of each 8KB row after softmax
// total: 159,383,552

extern "C" void kernel_launch(void* const* d_in, const int* in_sizes, int n_in,
                              void* d_out, int out_size, void* d_ws, size_t ws_size,
                              hipStream_t stream) {
  const float* x  = (const float*)d_in[0];
  const float* Wq = (const float*)d_in[1];
  const float* Wk = (const float*)d_in[2];
  const float* Wv = (const float*)d_in[3];
  const float* Wo = (const float*)d_in[4];
  const float* bO = (const float*)d_in[5];

  char* ws = (char*)d_ws;
  _Float16* xh  = (_Float16*)(ws + 0);
  _Float16* Wqh = (_Float16*)(ws + 16777216);
  _Float16* Wkh = (_Float16*)(ws + 18874368);
  _Float16* Wvh = (_Float16*)(ws + 20971520);
  _Float16* Woh = (_Float16*)(ws + 23068672);
  _Float16* Qh  = (_Float16*)(ws + 25165824);
  _Float16* Kh  = (_Float16*)(ws + 41943040);
  _Float16* Vt  = (_Float16*)(ws + 58720256);
  _Float16* Oh  = (_Float16*)(ws + 75497472);
  float*    Sb  = (float*)   (ws + 92274688);

  dim3 blk(256);

  // convert inputs to fp16
  cvt_f32_f16<<<8192, blk, 0, stream>>>(x,  xh,  2097152);
  cvt_f32_f16<<<1024, blk, 0, stream>>>(Wq, Wqh, 262144);
  cvt_f32_f16<<<1024, blk, 0, stream>>>(Wk, Wkh, 262144);
  cvt_f32_f16<<<1024, blk, 0, stream>>>(Wv, Wvh, 262144);
  cvt_f32_f16<<<1024, blk, 0, stream>>>(Wo, Woh, 262144);

  // Q = x @ Wq^T, K = x @ Wk^T  (fp16 out, normal layout)
  gemm_bt<0, false, false><<<dim3(8, 64, 1), blk, 0, stream>>>(
      xh, Wqh, Qh, nullptr, 1024, 1024, 1024, 1024, 0, 0, 0);
  gemm_bt<0, false, false><<<dim3(8, 64, 1), blk, 0, stream>>>(
      xh, Wkh, Kh, nullptr, 1024, 1024, 1024, 1024, 0, 0, 0);
  // V = x @ Wv^T, stored transposed as Vt[b][d][s]
  gemm_bt<1, false, false><<<dim3(8, 64, 1), blk, 0, stream>>>(
      xh, Wvh, Vt, nullptr, 1024, 1024, 1024, 0, 0, 0, 0);

  // S = Q @ K^T per batch (fp32), lower-triangular 128-tiles only
  gemm_bt<2, true, false><<<dim3(16, 16, 4), blk, 0, stream>>>(
      Qh, Kh, Sb, nullptr, 1024, 1024, 1024, 2048,
      2097152LL, 2097152LL, 4194304LL);

  // causal softmax -> fp16 P in upper half of each score row
  softmax_causal<<<8192, blk, 0, stream>>>(Sb);

  // O = P @ Vt^T  (K-loop clamped at diagonal tile edge)
  gemm_bt<0, false, true><<<dim3(8, 16, 4), blk, 0, stream>>>(
      (const _Float16*)Sb + 2048, Vt, Oh, nullptr, 2048, 4096, 2048, 1024,
      8388608LL, 2097152LL, 2097152LL);

  // out = O @ Wo^T + b_O  (fp32 to d_out)
  gemm_bt<3, false, false><<<dim3(8, 64, 1), blk, 0, stream>>>(
      Oh, Woh, (float*)d_out, bO, 1024, 1024, 1024, 1024, 0, 0, 0);
}

// Round 2
// 337.403 us; speedup vs baseline: 1.0674x; 1.0674x over previous
//
#include <hip/hip_runtime.h>
#include <cstdint>

typedef _Float16 f16x8 __attribute__((ext_vector_type(8)));
typedef _Float16 f16x4 __attribute__((ext_vector_type(4)));
typedef float    f32x4 __attribute__((ext_vector_type(4)));

#define AS1 __attribute__((address_space(1)))
#define AS3 __attribute__((address_space(3)))

__device__ __forceinline__ void load16_lds(const void* g, void* l) {
  __builtin_amdgcn_global_load_lds((AS1 void*)g, (AS3 void*)l, 16, 0, 0);
}

// ---------------- fp32 -> fp16 convert (vectorized) ----------------
__global__ __launch_bounds__(256) void cvt_f32_f16(const float* __restrict__ in,
                                                   _Float16* __restrict__ out, int n4) {
  int i = blockIdx.x * 256 + threadIdx.x;
  if (i >= n4) return;
  float4 v = ((const float4*)in)[i];
  f16x4 o;
  o[0] = (_Float16)v.x; o[1] = (_Float16)v.y; o[2] = (_Float16)v.z; o[3] = (_Float16)v.w;
  ((f16x4*)out)[i] = o;
}

// ---------------- causal softmax ----------------
// One block per row (g = b*2048 + i). Reads fp32 prefix [0..i], writes fp16 P
// into the UPPER HALF (byte offset +4096) of the same 8192-byte row, zero-padded
// up to the row's 128-tile edge so the PV GEMM never reads poison.
__global__ __launch_bounds__(256) void softmax_causal(float* __restrict__ Sbuf) {
  int g = blockIdx.x;
  int row = g & 2047;
  float* srow = Sbuf + (size_t)g * 2048;
  _Float16* prow = (_Float16*)srow + 2048;
  int L = row + 1;
  int Lp = ((row >> 7) + 1) << 7;
  int t = threadIdx.x;
  int lane = t & 63, w = t >> 6;

  float v[8];
  int cnt = 0;
  float mx = -3.0e38f;
  for (int j = t; j < L; j += 256) { float s = srow[j]; v[cnt++] = s; mx = fmaxf(mx, s); }

  __shared__ float sm[8];
  #pragma unroll
  for (int off = 32; off > 0; off >>= 1) mx = fmaxf(mx, __shfl_down(mx, off));
  if (lane == 0) sm[w] = mx;
  __syncthreads();
  if (t == 0) { float m2 = sm[0]; for (int q = 1; q < 4; q++) m2 = fmaxf(m2, sm[q]); sm[0] = m2; }
  __syncthreads();
  mx = sm[0];

  float sum = 0.f;
  for (int c = 0; c < cnt; c++) { float e = __expf(v[c] - mx); v[c] = e; sum += e; }
  #pragma unroll
  for (int off = 32; off > 0; off >>= 1) sum += __shfl_down(sum, off);
  if (lane == 0) sm[4 + w] = sum;
  __syncthreads();
  if (t == 0) sm[4] = 1.0f / (sm[4] + sm[5] + sm[6] + sm[7]);
  __syncthreads();
  float inv = sm[4];

  cnt = 0;
  for (int j = t; j < L; j += 256) prow[j] = (_Float16)(v[cnt++] * inv);
  for (int j = L + t; j < Lp; j += 256) prow[j] = (_Float16)0.0f;
}

// ---------------- generic A * B^T GEMM, m97 structure ----------------
// OUTMODE: 2 = fp32 normal, 3 = fp32 + bias.
template <int OUTMODE, bool CAUSAL_SKIP>
__global__ __launch_bounds__(256) void gemm_bt(
    const _Float16* __restrict__ A, const _Float16* __restrict__ B,
    void* __restrict__ Cv, const float* __restrict__ bias,
    int K, int lda, int ldb, int ldc,
    long long aBatch, long long bBatch, long long cBatch) {
  int bx = blockIdx.x, by = blockIdx.y, bz = blockIdx.z;
  if (CAUSAL_SKIP && bx > by) return;
  const _Float16* Ab = A + (long long)bz * aBatch + (long long)by * 128 * lda;
  const _Float16* Bb = B + (long long)bz * bBatch + (long long)bx * 128 * ldb;

  __shared__ _Float16 lA[128 * 32];
  __shared__ _Float16 lB[128 * 32];

  int tid = threadIdx.x;
  int r0 = tid >> 2;
  int c0 = (tid & 3) * 8;
  const _Float16* ga0 = Ab + (long long)r0 * lda + c0;
  const _Float16* ga1 = Ab + (long long)(r0 + 64) * lda + c0;
  const _Float16* gb0 = Bb + (long long)r0 * ldb + c0;
  const _Float16* gb1 = Bb + (long long)(r0 + 64) * ldb + c0;
  _Float16* la0 = lA + tid * 8;
  _Float16* la1 = lA + 2048 + tid * 8;
  _Float16* lb0 = lB + tid * 8;
  _Float16* lb1 = lB + 2048 + tid * 8;

  f32x4 acc[4][4] = {};
  int lane = tid & 63;
  int wv = tid >> 6;
  int wm = (wv & 1) * 64, wn = (wv >> 1) * 64;
  int l16 = lane & 15, quad = lane >> 4;
  const _Float16* raBase = lA + (wm + l16) * 32 + quad * 8;
  const _Float16* rbBase = lB + (wn + l16) * 32 + quad * 8;

  for (int kb = 0; kb < K; kb += 32) {
    __syncthreads();
    load16_lds(ga0, la0);
    load16_lds(ga1, la1);
    load16_lds(gb0, lb0);
    load16_lds(gb1, lb1);
    ga0 += 32; ga1 += 32; gb0 += 32; gb1 += 32;
    __syncthreads();
    f16x8 af[4], bfr[4];
    #pragma unroll
    for (int i = 0; i < 4; i++) af[i] = *(const f16x8*)(raBase + i * 512);
    #pragma unroll
    for (int j = 0; j < 4; j++) bfr[j] = *(const f16x8*)(rbBase + j * 512);
    #pragma unroll
    for (int i = 0; i < 4; i++)
      #pragma unroll
      for (int j = 0; j < 4; j++)
        acc[i][j] = __builtin_amdgcn_mfma_f32_16x16x32_f16(af[i], bfr[j], acc[i][j], 0, 0, 0);
  }

  int m0 = by * 128 + wm + quad * 4;
  int n0 = bx * 128 + wn + l16;

  if (OUTMODE == 2) {
    float* C = (float*)Cv + (long long)bz * cBatch;
    #pragma unroll
    for (int i = 0; i < 4; i++)
      #pragma unroll
      for (int j = 0; j < 4; j++)
        #pragma unroll
        for (int r = 0; r < 4; r++)
          C[(long long)(m0 + i * 16 + r) * ldc + (n0 + j * 16)] = acc[i][j][r];
  } else {
    float* C = (float*)Cv + (long long)bz * cBatch;
    #pragma unroll
    for (int j = 0; j < 4; j++) {
      float bj = bias[n0 + j * 16];
      #pragma unroll
      for (int i = 0; i < 4; i++)
        #pragma unroll
        for (int r = 0; r < 4; r++)
          C[(long long)(m0 + i * 16 + r) * ldc + (n0 + j * 16)] = acc[i][j][r] + bj;
    }
  }
}

// ---------------- fused QKV projection ----------------
// A = xh [8192][1024], B = Wcat [3072][1024] (Wq|Wk|Wv rows).
// grid (24, 64): bx<8 -> Qh, bx<16 -> Kh, else Vt transposed [b][d][s].
__global__ __launch_bounds__(256) void qkv_gemm(
    const _Float16* __restrict__ A, const _Float16* __restrict__ B,
    _Float16* __restrict__ Qh, _Float16* __restrict__ Kh, _Float16* __restrict__ Vt) {
  int bx = blockIdx.x, by = blockIdx.y;
  const _Float16* Ab = A + (long long)by * 128 * 1024;
  const _Float16* Bb = B + (long long)bx * 128 * 1024;

  __shared__ _Float16 lA[128 * 32];
  __shared__ _Float16 lB[128 * 32];

  int tid = threadIdx.x;
  int r0 = tid >> 2;
  int c0 = (tid & 3) * 8;
  const _Float16* ga0 = Ab + (long long)r0 * 1024 + c0;
  const _Float16* ga1 = Ab + (long long)(r0 + 64) * 1024 + c0;
  const _Float16* gb0 = Bb + (long long)r0 * 1024 + c0;
  const _Float16* gb1 = Bb + (long long)(r0 + 64) * 1024 + c0;
  _Float16* la0 = lA + tid * 8;
  _Float16* la1 = lA + 2048 + tid * 8;
  _Float16* lb0 = lB + tid * 8;
  _Float16* lb1 = lB + 2048 + tid * 8;

  f32x4 acc[4][4] = {};
  int lane = tid & 63;
  int wv = tid >> 6;
  int wm = (wv & 1) * 64, wn = (wv >> 1) * 64;
  int l16 = lane & 15, quad = lane >> 4;
  const _Float16* raBase = lA + (wm + l16) * 32 + quad * 8;
  const _Float16* rbBase = lB + (wn + l16) * 32 + quad * 8;

  for (int kb = 0; kb < 1024; kb += 32) {
    __syncthreads();
    load16_lds(ga0, la0);
    load16_lds(ga1, la1);
    load16_lds(gb0, lb0);
    load16_lds(gb1, lb1);
    ga0 += 32; ga1 += 32; gb0 += 32; gb1 += 32;
    __syncthreads();
    f16x8 af[4], bfr[4];
    #pragma unroll
    for (int i = 0; i < 4; i++) af[i] = *(const f16x8*)(raBase + i * 512);
    #pragma unroll
    for (int j = 0; j < 4; j++) bfr[j] = *(const f16x8*)(rbBase + j * 512);
    #pragma unroll
    for (int i = 0; i < 4; i++)
      #pragma unroll
      for (int j = 0; j < 4; j++)
        acc[i][j] = __builtin_amdgcn_mfma_f32_16x16x32_f16(af[i], bfr[j], acc[i][j], 0, 0, 0);
  }

  int m0 = by * 128 + wm + quad * 4;
  int n0 = bx * 128 + wn + l16;

  if (bx < 16) {
    _Float16* C = (bx < 8) ? Qh : Kh;
    int nr = n0 & 1023;
    #pragma unroll
    for (int i = 0; i < 4; i++)
      #pragma unroll
      for (int j = 0; j < 4; j++)
        #pragma unroll
        for (int r = 0; r < 4; r++)
          C[(long long)(m0 + i * 16 + r) * 1024 + (nr + j * 16)] = (_Float16)acc[i][j][r];
  } else {
    int d0 = n0 - 2048;
    #pragma unroll
    for (int i = 0; i < 4; i++) {
      long long mm = m0 + i * 16;
      long long b = mm >> 11;
      long long s = mm & 2047;
      #pragma unroll
      for (int j = 0; j < 4; j++) {
        f16x4 pk;
        #pragma unroll
        for (int r = 0; r < 4; r++) pk[r] = (_Float16)acc[i][j][r];
        *(f16x4*)(Vt + (b << 21) + (long long)(d0 + j * 16) * 2048 + s) = pk;
      }
    }
  }
}

// ---------------- split-K PV GEMM ----------------
// O = P @ Vt^T, K split at 1024. grid (8, 24, 4).
// cy<8: by=cy, chunk 0.  cy>=8: by=8+(cy-8)/2, chunk=(cy-8)%2.
// chunk0 -> P0 [b][2048][1024] fp32 (full coverage, plain stores)
// chunk1 -> P1 [b][1024][1024] fp32 (rows 1024..2047, plain stores)
__global__ __launch_bounds__(256) void pv_splitk(
    const _Float16* __restrict__ P,   // Sb upper halves: lda=4096, batch 8388608
    const _Float16* __restrict__ Vt,  // [b][1024][2048]
    float* __restrict__ P0, float* __restrict__ P1) {
  int bx = blockIdx.x, cy = blockIdx.y, bz = blockIdx.z;
  int by, c;
  if (cy < 8) { by = cy; c = 0; }
  else { int q = cy - 8; by = 8 + (q >> 1); c = q & 1; }
  int kmax = (by + 1) * 128;
  int k0 = c * 1024;
  int klen = min(kmax, k0 + 1024) - k0;

  const _Float16* Ab = P + (long long)bz * 8388608LL + (long long)by * 128 * 4096 + k0;
  const _Float16* Bb = Vt + (long long)bz * 2097152LL + (long long)bx * 128 * 2048 + k0;

  __shared__ _Float16 lA[128 * 32];
  __shared__ _Float16 lB[128 * 32];

  int tid = threadIdx.x;
  int r0 = tid >> 2;
  int c0 = (tid & 3) * 8;
  const _Float16* ga0 = Ab + (long long)r0 * 4096 + c0;
  const _Float16* ga1 = Ab + (long long)(r0 + 64) * 4096 + c0;
  const _Float16* gb0 = Bb + (long long)r0 * 2048 + c0;
  const _Float16* gb1 = Bb + (long long)(r0 + 64) * 2048 + c0;
  _Float16* la0 = lA + tid * 8;
  _Float16* la1 = lA + 2048 + tid * 8;
  _Float16* lb0 = lB + tid * 8;
  _Float16* lb1 = lB + 2048 + tid * 8;

  f32x4 acc[4][4] = {};
  int lane = tid & 63;
  int wv = tid >> 6;
  int wm = (wv & 1) * 64, wn = (wv >> 1) * 64;
  int l16 = lane & 15, quad = lane >> 4;
  const _Float16* raBase = lA + (wm + l16) * 32 + quad * 8;
  const _Float16* rbBase = lB + (wn + l16) * 32 + quad * 8;

  for (int kb = 0; kb < klen; kb += 32) {
    __syncthreads();
    load16_lds(ga0, la0);
    load16_lds(ga1, la1);
    load16_lds(gb0, lb0);
    load16_lds(gb1, lb1);
    ga0 += 32; ga1 += 32; gb0 += 32; gb1 += 32;
    __syncthreads();
    f16x8 af[4], bfr[4];
    #pragma unroll
    for (int i = 0; i < 4; i++) af[i] = *(const f16x8*)(raBase + i * 512);
    #pragma unroll
    for (int j = 0; j < 4; j++) bfr[j] = *(const f16x8*)(rbBase + j * 512);
    #pragma unroll
    for (int i = 0; i < 4; i++)
      #pragma unroll
      for (int j = 0; j < 4; j++)
        acc[i][j] = __builtin_amdgcn_mfma_f32_16x16x32_f16(af[i], bfr[j], acc[i][j], 0, 0, 0);
  }

  int m0 = by * 128 + wm + quad * 4;
  int n0 = bx * 128 + wn + l16;

  if (c == 0) {
    float* C = P0 + (long long)bz * 2097152LL;
    #pragma unroll
    for (int i = 0; i < 4; i++)
      #pragma unroll
      for (int j = 0; j < 4; j++)
        #pragma unroll
        for (int r = 0; r < 4; r++)
          C[(long long)(m0 + i * 16 + r) * 1024 + (n0 + j * 16)] = acc[i][j][r];
  } else {
    float* C = P1 + (long long)bz * 1048576LL;
    int mr = m0 - 1024;
    #pragma unroll
    for (int i = 0; i < 4; i++)
      #pragma unroll
      for (int j = 0; j < 4; j++)
        #pragma unroll
        for (int r = 0; r < 4; r++)
          C[(long long)(mr + i * 16 + r) * 1024 + (n0 + j * 16)] = acc[i][j][r];
  }
}

// ---------------- PV reduce: Oh = f16(P0 + P1[rows>=1024]) ----------------
__global__ __launch_bounds__(256) void pv_reduce(const float* __restrict__ P0,
                                                 const float* __restrict__ P1,
                                                 _Float16* __restrict__ Oh) {
  int i = blockIdx.x * 256 + threadIdx.x;  // float4 index over 8M floats
  if (i >= 2097152) return;
  float4 v = ((const float4*)P0)[i];
  int f = i * 4;
  int m = f >> 10;
  int r = m & 2047;
  if (r >= 1024) {
    int bz = m >> 11;
    long long off = ((long long)bz * 1048576LL + (long long)(r - 1024) * 1024 + (f & 1023)) >> 2;
    float4 w = ((const float4*)P1)[off];
    v.x += w.x; v.y += w.y; v.z += w.z; v.w += w.w;
  }
  f16x4 o;
  o[0] = (_Float16)v.x; o[1] = (_Float16)v.y; o[2] = (_Float16)v.z; o[3] = (_Float16)v.w;
  ((f16x4*)Oh)[i] = o;
}

// ---------------- workspace layout (bytes) ----------------
// xh  : 0          16,777,216   x fp16              -> P1 (16 MB) during PV
// Wcat: 16777216    6,291,456   Wq|Wk|Wv fp16 [3072][1024]
// Woh : 23068672    2,097,152
// Qh  : 25165824   16,777,216   -> P0 first half during PV
// Kh  : 41943040   16,777,216   -> P0 second half during PV
// Vt  : 58720256   16,777,216   [b][d=1024][s=2048]
// Oh  : 75497472   16,777,216
// Sb  : 92274688   67,108,864   fp32 scores; fp16 P in upper 4KB of each row
// total: 159,383,552

extern "C" void kernel_launch(void* const* d_in, const int* in_sizes, int n_in,
                              void* d_out, int out_size, void* d_ws, size_t ws_size,
                              hipStream_t stream) {
  const float* x  = (const float*)d_in[0];
  const float* Wq = (const float*)d_in[1];
  const float* Wk = (const float*)d_in[2];
  const float* Wv = (const float*)d_in[3];
  const float* Wo = (const float*)d_in[4];
  const float* bO = (const float*)d_in[5];

  char* ws = (char*)d_ws;
  _Float16* xh   = (_Float16*)(ws + 0);
  _Float16* Wcat = (_Float16*)(ws + 16777216);
  _Float16* Woh  = (_Float16*)(ws + 23068672);
  _Float16* Qh   = (_Float16*)(ws + 25165824);
  _Float16* Kh   = (_Float16*)(ws + 41943040);
  _Float16* Vt   = (_Float16*)(ws + 58720256);
  _Float16* Oh   = (_Float16*)(ws + 75497472);
  float*    Sb   = (float*)   (ws + 92274688);
  float*    P0   = (float*)   (ws + 25165824);  // aliases Qh+Kh (dead by PV)
  float*    P1   = (float*)   (ws + 0);         // aliases xh (dead by PV)

  dim3 blk(256);

  cvt_f32_f16<<<8192, blk, 0, stream>>>(x,  xh,  2097152);
  cvt_f32_f16<<<1024, blk, 0, stream>>>(Wq, Wcat,               262144);
  cvt_f32_f16<<<1024, blk, 0, stream>>>(Wk, Wcat + 1048576,     262144);
  cvt_f32_f16<<<1024, blk, 0, stream>>>(Wv, Wcat + 2097152,     262144);
  cvt_f32_f16<<<1024, blk, 0, stream>>>(Wo, Woh,                262144);

  // fused Q/K/V projection (V stored transposed)
  qkv_gemm<<<dim3(24, 64, 1), blk, 0, stream>>>(xh, Wcat, Qh, Kh, Vt);

  // S = Q @ K^T per batch (fp32), lower-triangular 128-tiles only
  gemm_bt<2, true><<<dim3(16, 16, 4), blk, 0, stream>>>(
      Qh, Kh, Sb, nullptr, 1024, 1024, 1024, 2048,
      2097152LL, 2097152LL, 4194304LL);

  // causal softmax -> fp16 P in upper half of each score row
  softmax_causal<<<8192, blk, 0, stream>>>(Sb);

  // O = P @ Vt^T with split-K (balanced, deterministic two-partial scheme)
  pv_splitk<<<dim3(8, 24, 4), blk, 0, stream>>>(
      (const _Float16*)Sb + 2048, Vt, P0, P1);
  pv_reduce<<<8192, blk, 0, stream>>>(P0, P1, Oh);

  // out = O @ Wo^T + b_O
  gemm_bt<3, false><<<dim3(8, 64, 1), blk, 0, stream>>>(
      Oh, Woh, (float*)d_out, bO, 1024, 1024, 1024, 1024, 0, 0, 0);
}